// Round 3
// baseline (441.677 us; speedup 1.0000x reference)
//
#include <hip/hip_runtime.h>
#include <math.h>

#define N_NODES 50000
#define N_EDGES 400000
#define F_DIM   128
#define N_RBF   20
#define EC      4          // edges per chunk in gather
#define SCAN_B  256
#define N_CHUNK ((N_NODES + SCAN_B - 1) / SCAN_B)   // 196

// ---------------------------------------------------------------------------
// phi_table[t] = silu(emb_table[t] @ w_phi1 + b_phi1) @ w_phi2 + b_phi2
// ---------------------------------------------------------------------------
__global__ void phi_table_kernel(const float* __restrict__ emb_table,
                                 const float* __restrict__ w_phi1,
                                 const float* __restrict__ b_phi1,
                                 const float* __restrict__ w_phi2,
                                 const float* __restrict__ b_phi2,
                                 float* __restrict__ phi_table) {
    __shared__ float emb_s[F_DIM];
    __shared__ float h_s[F_DIM];
    const int t = blockIdx.x;
    const int o = threadIdx.x;
    if (o < F_DIM) emb_s[o] = emb_table[t * F_DIM + o];
    __syncthreads();
    if (o < F_DIM) {
        float acc = b_phi1[o];
#pragma unroll 8
        for (int k = 0; k < F_DIM; ++k)
            acc = fmaf(emb_s[k], w_phi1[k * F_DIM + o], acc);
        h_s[o] = acc / (1.0f + expf(-acc));   // silu
    }
    __syncthreads();
    float a2 = b_phi2[o];
#pragma unroll 8
    for (int k = 0; k < F_DIM; ++k)
        a2 = fmaf(h_s[k], w_phi2[k * (3 * F_DIM) + o], a2);
    phi_table[t * (3 * F_DIM) + o] = a2;
}

__global__ void count_kernel(const int* __restrict__ edst, int* __restrict__ counts) {
    const int e = blockIdx.x * blockDim.x + threadIdx.x;
    if (e < N_EDGES) atomicAdd(&counts[edst[e]], 1);
}

__global__ void scan_partial_kernel(const int* __restrict__ counts,
                                    int* __restrict__ partial,
                                    int* __restrict__ chunk_sums) {
    __shared__ int s[SCAN_B];
    const int tid = threadIdx.x;
    const int gid = blockIdx.x * SCAN_B + tid;
    const int v = (gid < N_NODES) ? counts[gid] : 0;
    s[tid] = v;
    __syncthreads();
    for (int d = 1; d < SCAN_B; d <<= 1) {
        const int t = (tid >= d) ? s[tid - d] : 0;
        __syncthreads();
        s[tid] += t;
        __syncthreads();
    }
    if (gid < N_NODES) partial[gid] = s[tid] - v;
    if (tid == SCAN_B - 1) chunk_sums[blockIdx.x] = s[tid];
}

__global__ void scan_sums_kernel(int* __restrict__ chunk_sums,
                                 int* __restrict__ chunk_pref) {
    __shared__ int s[SCAN_B];
    const int tid = threadIdx.x;
    const int v = (tid < N_CHUNK) ? chunk_sums[tid] : 0;
    s[tid] = v;
    __syncthreads();
    for (int d = 1; d < SCAN_B; d <<= 1) {
        const int t = (tid >= d) ? s[tid - d] : 0;
        __syncthreads();
        s[tid] += t;
        __syncthreads();
    }
    if (tid < N_CHUNK) chunk_pref[tid] = s[tid] - v;
}

__global__ void finalize_offsets_kernel(const int* __restrict__ partial,
                                        const int* __restrict__ chunk_pref,
                                        int* __restrict__ offsets,
                                        int* __restrict__ cursor) {
    const int i = blockIdx.x * blockDim.x + threadIdx.x;
    if (i >= N_NODES) return;
    const int o = partial[i] + chunk_pref[i >> 8];
    offsets[i] = o;
    cursor[i]  = o;
}

// ---------------------------------------------------------------------------
// Edge-parallel precompute + CSR fill. Per edge, one 32B record at slot p:
//   rec[2p]   = (px, py, pz, d)
//   rec[2p+1] = (j, t, sin(a)/d, 2*cos(a))   [a = pi*d/5]
// ---------------------------------------------------------------------------
__global__ void edge_pre_kernel(const float* __restrict__ pos,
                                const int* __restrict__ z,
                                const int* __restrict__ esrc,
                                const int* __restrict__ edst,
                                int* __restrict__ cursor,
                                float4* __restrict__ rec) {
    const int e = blockIdx.x * blockDim.x + threadIdx.x;
    if (e >= N_EDGES) return;
    const int j = esrc[e];
    const int i = edst[e];
    const int p = atomicAdd(&cursor[i], 1);

    const float px = pos[3 * i + 0] - pos[3 * j + 0];
    const float py = pos[3 * i + 1] - pos[3 * j + 1];
    const float pz = pos[3 * i + 2] - pos[3 * j + 2];
    const float d = sqrtf(px * px + py * py + pz * pz);
    const float inv_d = 1.0f / d;

    float sa, ca;
    sincosf(0.6283185307179586f * d, &sa, &ca);   // pi*d/5

    rec[2 * p] = make_float4(px, py, pz, d);
    float4 b;
    b.x = __int_as_float(j);
    b.y = __int_as_float(z[j]);
    b.z = sa * inv_d;
    b.w = 2.0f * ca;
    rec[2 * p + 1] = b;
}

// ---------------------------------------------------------------------------
// Gather: 128-thread group per node (2/block). Thread f owns outputs
// f, 128+f, 256+f.
//
// R2 post-mortem: the compiler will NOT hold 60 loop-invariant weights live
// (remats or spills, both rounds proved it). R3: restructure so only 3
// weights are EVER live — edges processed in chunks of EC=4 with the RBF
// index n as the outer loop of the hot block. Weight loads: 60/edge -> 15/edge,
// plus their address VALU disappears. Tail slots masked by zeroing ph
// (kills all their contributions exactly). eq/phi gather latency hides
// under the same chunk's 320-FMA block; next chunk's recs are prefetched
// before the FMA block.
// ---------------------------------------------------------------------------
__global__ void __launch_bounds__(256, 2)
gather_kernel(const float* __restrict__ eq,
              const float* __restrict__ emb_table,
              const float* __restrict__ phi_table,
              const float* __restrict__ w_rbf,
              const float* __restrict__ b_rbf,
              const int* __restrict__ z,
              const float4* __restrict__ rec,
              const int* __restrict__ offsets,
              const int* __restrict__ counts,
              float* __restrict__ out_emb,
              float* __restrict__ out_eq) {
    const int tid = threadIdx.x;
    const int grp = tid >> 7;
    const int f   = tid & 127;
    const int i   = blockIdx.x * 2 + grp;
    if (i >= N_NODES) return;

    const int start = offsets[i];
    const int cnt   = counts[i];

    const float br1 = b_rbf[f];
    const float br2 = b_rbf[F_DIM + f];
    const float br3 = b_rbf[2 * F_DIM + f];
    const float* wbase = w_rbf + f;

    float accE = 0.f, ax = 0.f, ay = 0.f, az = 0.f;

    if (cnt > 0) {
        const int last = cnt - 1;

        // prologue: chunk 0 records
        float4 A[EC], Bv[EC];
#pragma unroll
        for (int s = 0; s < EC; ++s) {
            const int p = start + min(s, last);
            A[s]  = rec[2 * p];
            Bv[s] = rec[2 * p + 1];
        }

        for (int base = 0; base < cnt; base += EC) {
            // unpack current chunk, init Chebyshev state
            float m[EC], tc[EC], tm1[EC], twoc[EC];
            int   jj[EC], tt[EC];
#pragma unroll
            for (int s = 0; s < EC; ++s) {
                m[s]    = (base + s < cnt) ? 1.0f : 0.0f;
                jj[s]   = __float_as_int(Bv[s].x);
                tt[s]   = __float_as_int(Bv[s].y);
                tc[s]   = Bv[s].z;
                tm1[s]  = 0.0f;
                twoc[s] = Bv[s].w;
            }

            // issue eq/phi gathers for current chunk (latency hidden by FMA block)
            float eqv[EC][3], ph[EC][3];
#pragma unroll
            for (int s = 0; s < EC; ++s) {
                const float* ej = eq + ((size_t)jj[s] * F_DIM + f) * 3;
                eqv[s][0] = ej[0]; eqv[s][1] = ej[1]; eqv[s][2] = ej[2];
                const float* pt = phi_table + tt[s] * (3 * F_DIM) + f;
                ph[s][0] = pt[0]; ph[s][1] = pt[F_DIM]; ph[s][2] = pt[2 * F_DIM];
            }

            // prefetch next chunk's records (clamped; harmless dup on tail)
            float4 An[EC], Bn[EC];
#pragma unroll
            for (int s = 0; s < EC; ++s) {
                const int p = start + min(base + EC + s, last);
                An[s] = rec[2 * p];
                Bn[s] = rec[2 * p + 1];
            }

            // hot block: n outer, only 3 weights live at a time
            float W1[EC], W2[EC], W3[EC];
#pragma unroll
            for (int s = 0; s < EC; ++s) { W1[s] = br1; W2[s] = br2; W3[s] = br3; }
#pragma unroll
            for (int n = 0; n < N_RBF; ++n) {
                const float w1 = wbase[n * (3 * F_DIM)];
                const float w2 = wbase[n * (3 * F_DIM) + F_DIM];
                const float w3 = wbase[n * (3 * F_DIM) + 2 * F_DIM];
#pragma unroll
                for (int s = 0; s < EC; ++s) {
                    W1[s] = fmaf(tc[s], w1, W1[s]);
                    W2[s] = fmaf(tc[s], w2, W2[s]);
                    W3[s] = fmaf(tc[s], w3, W3[s]);
                    const float tn = fmaf(twoc[s], tc[s], -tm1[s]);
                    tm1[s] = tc[s]; tc[s] = tn;
                }
            }

            // epilogue: combine (masked)
#pragma unroll
            for (int s = 0; s < EC; ++s) {
                const float p0 = m[s] * ph[s][0];
                const float p1 = m[s] * ph[s][1];
                const float p2 = m[s] * ph[s][2];
                accE = fmaf(p0, W1[s], accE);
                const float s2 = p1 * W2[s];
                const float s3 = p2 * W3[s] * A[s].w;
                ax = fmaf(eqv[s][0], s2, fmaf(s3, A[s].x, ax));
                ay = fmaf(eqv[s][1], s2, fmaf(s3, A[s].y, ay));
                az = fmaf(eqv[s][2], s2, fmaf(s3, A[s].z, az));
            }

            // rotate pipeline
#pragma unroll
            for (int s = 0; s < EC; ++s) { A[s] = An[s]; Bv[s] = Bn[s]; }
        }
    }

    out_emb[(size_t)i * F_DIM + f] = emb_table[z[i] * F_DIM + f] + accE;

    const float* ei = eq     + ((size_t)i * F_DIM + f) * 3;
    float*       od = out_eq + ((size_t)i * F_DIM + f) * 3;
    od[0] = ei[0] + ax;
    od[1] = ei[1] + ay;
    od[2] = ei[2] + az;
}

// ---------------------------------------------------------------------------
extern "C" void kernel_launch(void* const* d_in, const int* in_sizes, int n_in,
                              void* d_out, int out_size, void* d_ws, size_t ws_size,
                              hipStream_t stream) {
    const float* pos       = (const float*)d_in[0];
    const float* eq        = (const float*)d_in[1];
    const float* emb_table = (const float*)d_in[2];
    const float* w_phi1    = (const float*)d_in[3];
    const float* b_phi1    = (const float*)d_in[4];
    const float* w_phi2    = (const float*)d_in[5];
    const float* b_phi2    = (const float*)d_in[6];
    const float* w_rbf     = (const float*)d_in[7];
    const float* b_rbf     = (const float*)d_in[8];
    const int*   z         = (const int*)d_in[9];
    const int*   esrc      = (const int*)d_in[10];
    const int*   edst      = (const int*)d_in[11];

    float* out_emb = (float*)d_out;                               // [N, F]
    float* out_eq  = (float*)d_out + (size_t)N_NODES * F_DIM;     // [N, F, 3]

    // workspace layout (16B-aligned chunks)
    char* ws = (char*)d_ws;
    float4* rec        = (float4*)ws;  ws += (size_t)N_EDGES * 32;
    float*  phi_table  = (float*)ws;   ws += 100 * 3 * F_DIM * 4;
    int*    counts     = (int*)ws;     ws += N_NODES * 4;
    int*    partial    = (int*)ws;     ws += N_NODES * 4;
    int*    offsets    = (int*)ws;     ws += N_NODES * 4;
    int*    cursor     = (int*)ws;     ws += N_NODES * 4;
    int*    chunk_sums = (int*)ws;     ws += SCAN_B * 4;
    int*    chunk_pref = (int*)ws;     ws += SCAN_B * 4;

    hipMemsetAsync(counts, 0, N_NODES * sizeof(int), stream);
    phi_table_kernel<<<100, 3 * F_DIM, 0, stream>>>(emb_table, w_phi1, b_phi1,
                                                    w_phi2, b_phi2, phi_table);
    count_kernel<<<(N_EDGES + 255) / 256, 256, 0, stream>>>(edst, counts);
    scan_partial_kernel<<<N_CHUNK, SCAN_B, 0, stream>>>(counts, partial, chunk_sums);
    scan_sums_kernel<<<1, SCAN_B, 0, stream>>>(chunk_sums, chunk_pref);
    finalize_offsets_kernel<<<(N_NODES + 255) / 256, 256, 0, stream>>>(
        partial, chunk_pref, offsets, cursor);
    edge_pre_kernel<<<(N_EDGES + 255) / 256, 256, 0, stream>>>(
        pos, z, esrc, edst, cursor, rec);
    gather_kernel<<<(N_NODES + 1) / 2, 256, 0, stream>>>(
        eq, emb_table, phi_table, w_rbf, b_rbf, z, rec,
        offsets, counts, out_emb, out_eq);
}